// Round 8
// baseline (170.926 us; speedup 1.0000x reference)
//
#include <hip/hip_runtime.h>

#define NN    100000
#define NE    1600000
#define NE4   (NE / 4)
#define D     128
#define P     32                 // edge slices
#define BINS  8                  // node bins
#define BSZ   12512              // nodes per bin (50 KB LDS); BINS*BSZ = 100096 >= NN
#define NNP   (BINS * BSZ)       // padded node stride (100096 = 391*256)
#define NNP4  (NNP / 4)          // 25024 = 391*64
#define SL4   (NE4 / P)          // int4 edges per slice = 12500 (exact)
#define RB    391                // node-chunk blocks (391*64 float4 == NNP4 exactly)

// XCD swizzle: blocks scanning the same edge slice s land on one XCD (blk%8 == s%8),
// so each slice is HBM-fetched once and L2-served to the other 7 bin-blocks.
__device__ __forceinline__ void decode(int blk, int& b, int& s) {
    int x = blk & 7, y = blk >> 3;     // y in [0,32)
    s = (y & 3) * 8 + x;               // slice  [0,32)
    b = y >> 2;                        // bin    [0,8)
}

// Generic binned scatter body: dst[s][v] += val[e] where key[e]==v, gated on bin.
__device__ __forceinline__ void scat_body(const int4* __restrict__ key4,
                                          const float4* __restrict__ val4,
                                          float* __restrict__ dst, int idx) {
    __shared__ float bin[BSZ];         // 50 KB -> 2 blocks/CU (32 waves w/ 1024 thr)
    int b, s; decode(idx, b, s);
    float4* bin4 = (float4*)bin;
    for (int i = threadIdx.x; i < BSZ / 4; i += 1024) bin4[i] = make_float4(0, 0, 0, 0);
    __syncthreads();
    const int lo = b * BSZ;
    const int e1 = (s + 1) * SL4;
    for (int e = s * SL4 + threadIdx.x; e < e1; e += 1024) {
        int4 k = key4[e];
        float4 v = val4[e];
        int r0 = k.x - lo, r1 = k.y - lo, r2 = k.z - lo, r3 = k.w - lo;
        if ((unsigned)r0 < (unsigned)BSZ) atomicAdd(&bin[r0], v.x);
        if ((unsigned)r1 < (unsigned)BSZ) atomicAdd(&bin[r1], v.y);
        if ((unsigned)r2 < (unsigned)BSZ) atomicAdd(&bin[r2], v.z);
        if ((unsigned)r3 < (unsigned)BSZ) atomicAdd(&bin[r3], v.w);
    }
    __syncthreads();
    float4* out = (float4*)(dst + (size_t)s * NNP + lo);
    for (int i = threadIdx.x; i < BSZ / 4; i += 1024) out[i] = bin4[i];
}

// ---- scatter 1: degree partials pA[s][v] = sum_{col=v, e in slice s} w[e] ----
__global__ __launch_bounds__(1024) void k_scat1(const int4* __restrict__ col4,
                                                const float4* __restrict__ w4,
                                                float* __restrict__ pA) {
    scat_body(col4, w4, pA, blockIdx.x);
}

// ---- reduce 1: dinv = rsqrt(1 + deg); block 0: s1 = colsum(W1), accg = 0 ----
__global__ __launch_bounds__(256) void k_red1(const float* __restrict__ pA,
                                              const float* __restrict__ W1,
                                              float* __restrict__ dinv,
                                              float* __restrict__ s1,
                                              float* __restrict__ accg) {
    __shared__ float4 sS[256];
    __shared__ float red[256];
    const int t = threadIdx.x, q = t & 63, g = t >> 6;
    const int v4 = blockIdx.x * 64 + q;            // 391*64 == NNP4 exactly
    float4 a = make_float4(0.f, 0.f, 0.f, 0.f);
    #pragma unroll
    for (int k = 0; k < P / 4; ++k) {              // slice-split: group g sums 8 slices
        int ss = g * (P / 4) + k;
        float4 p = ((const float4*)(pA + (size_t)ss * NNP))[v4];
        a.x += p.x; a.y += p.y; a.z += p.z; a.w += p.w;
    }
    sS[t] = a;
    __syncthreads();
    if (t < 64) {
        float4 a0 = sS[t], a1 = sS[64 + t], a2 = sS[128 + t], a3 = sS[192 + t];
        float4 d;
        d.x = rsqrtf(1.f + a0.x + a1.x + a2.x + a3.x);   // +1 = self-loop weight
        d.y = rsqrtf(1.f + a0.y + a1.y + a2.y + a3.y);
        d.z = rsqrtf(1.f + a0.z + a1.z + a2.z + a3.z);
        d.w = rsqrtf(1.f + a0.w + a1.w + a2.w + a3.w);
        ((float4*)dinv)[v4] = d;
    }
    if (blockIdx.x == 0) {                         // s1[j] = sum_i W1[i][j]; accg = 0
        int j = t & (D - 1), h = t >> 7;
        float p = 0.f;
        #pragma unroll 16
        for (int r = h * 64; r < h * 64 + 64; ++r) p += W1[r * D + j];
        red[t] = p;
        __syncthreads();
        if (t < D) {
            s1[t] = red[t] + red[t + D];
            accg[t] = 0.f;                         // ws re-poisoned each call
        }
    }
}

// ---- val precompute: valS[e] = w*dinv[row], valU[e] = w*dinv[col]  (1 gather/edge/dir) ----
__global__ __launch_bounds__(256) void k_val(const int4* __restrict__ row4,
                                             const int4* __restrict__ col4,
                                             const float4* __restrict__ w4,
                                             const float* __restrict__ dinv,
                                             float4* __restrict__ valS,
                                             float4* __restrict__ valU) {
    int e4 = blockIdx.x * 256 + threadIdx.x;
    if (e4 >= NE4) return;
    int4 r = row4[e4];
    int4 c = col4[e4];
    float4 w = w4[e4];
    float4 vs, vu;
    vs.x = w.x * dinv[r.x]; vs.y = w.y * dinv[r.y];
    vs.z = w.z * dinv[r.z]; vs.w = w.w * dinv[r.w];
    vu.x = w.x * dinv[c.x]; vu.y = w.y * dinv[c.y];
    vu.z = w.z * dinv[c.z]; vu.w = w.w * dinv[c.w];
    valS[e4] = vs;
    valU[e4] = vu;
}

// ---- scatter 2: S (col-keyed, valS) and U (row-keyed, valU) halves in one launch ----
__global__ __launch_bounds__(1024) void k_scatSU(const int4* __restrict__ col4,
                                                 const int4* __restrict__ row4,
                                                 const float4* __restrict__ valS4,
                                                 const float4* __restrict__ valU4,
                                                 float* __restrict__ pS,
                                                 float* __restrict__ pU) {
    int half = blockIdx.x >> 8;
    scat_body(half ? row4 : col4, half ? valU4 : valS4, half ? pU : pS, blockIdx.x & 255);
}

// ---- reduce 2 + node-dot: c = dinv*(S+dinv), wgt = dinv*(U+dinv);
//      accg[j] += sum_v wgt * relu(c*s1[j] + b1[j]) ----
__global__ __launch_bounds__(256) void k_red2node(const float* __restrict__ pS,
                                                  const float* __restrict__ pU,
                                                  const float* __restrict__ dinv,
                                                  const float* __restrict__ s1,
                                                  const float* __restrict__ b1,
                                                  float* __restrict__ accg) {
    __shared__ float4 sS[256], sU[256];
    __shared__ float4 ldsC[64], ldsW[64];
    __shared__ float red[D];
    const int t = threadIdx.x;
    const int q = t & 63;
    const int grp = t >> 6;
    const int v4 = blockIdx.x * 64 + q;            // 391*64 == NNP4 exactly

    float4 S = make_float4(0, 0, 0, 0), U = make_float4(0, 0, 0, 0);
    #pragma unroll
    for (int k = 0; k < P / 4; ++k) {
        int ss = grp * (P / 4) + k;
        float4 a = ((const float4*)(pS + (size_t)ss * NNP))[v4];
        float4 u = ((const float4*)(pU + (size_t)ss * NNP))[v4];
        S.x += a.x; S.y += a.y; S.z += a.z; S.w += a.w;
        U.x += u.x; U.y += u.y; U.z += u.z; U.w += u.w;
    }
    sS[t] = S; sU[t] = U;
    __syncthreads();
    if (t < 64) {
        float4 S0 = sS[t], S1 = sS[64 + t], S2 = sS[128 + t], S3 = sS[192 + t];
        float4 U0 = sU[t], U1 = sU[64 + t], U2 = sU[128 + t], U3 = sU[192 + t];
        float4 Sa, Ua;
        Sa.x = S0.x + S1.x + S2.x + S3.x; Sa.y = S0.y + S1.y + S2.y + S3.y;
        Sa.z = S0.z + S1.z + S2.z + S3.z; Sa.w = S0.w + S1.w + S2.w + S3.w;
        Ua.x = U0.x + U1.x + U2.x + U3.x; Ua.y = U0.y + U1.y + U2.y + U3.y;
        Ua.z = U0.z + U1.z + U2.z + U3.z; Ua.w = U0.w + U1.w + U2.w + U3.w;
        float4 dv = ((const float4*)dinv)[v4];
        float4 cc, ww;
        cc.x = dv.x * (Sa.x + dv.x); cc.y = dv.y * (Sa.y + dv.y);
        cc.z = dv.z * (Sa.z + dv.z); cc.w = dv.w * (Sa.w + dv.w);
        ww.x = dv.x * (Ua.x + dv.x); ww.y = dv.y * (Ua.y + dv.y);
        ww.z = dv.z * (Ua.z + dv.z); ww.w = dv.w * (Ua.w + dv.w);
        int v0 = v4 * 4;                           // mask padded fake nodes
        if (v0 + 0 >= NN) ww.x = 0.f;
        if (v0 + 1 >= NN) ww.y = 0.f;
        if (v0 + 2 >= NN) ww.z = 0.f;
        if (v0 + 3 >= NN) ww.w = 0.f;
        ldsC[t] = cc; ldsW[t] = ww;
    }
    __syncthreads();

    const int j = t & (D - 1), g = t >> 7;
    const float sj = s1[j], bj = b1[j];
    float acc = 0.f;
    #pragma unroll
    for (int k = 0; k < 32; ++k) {
        float4 c4 = ldsC[g * 32 + k];              // wave-uniform LDS broadcast
        float4 w4 = ldsW[g * 32 + k];
        acc += w4.x * fmaxf(fmaf(c4.x, sj, bj), 0.f);
        acc += w4.y * fmaxf(fmaf(c4.y, sj, bj), 0.f);
        acc += w4.z * fmaxf(fmaf(c4.z, sj, bj), 0.f);
        acc += w4.w * fmaxf(fmaf(c4.w, sj, bj), 0.f);
    }
    if (g) red[j] = acc;
    __syncthreads();
    if (!g) atomicAdd(&accg[j], acc + red[j]);
}

// ---- gemv: out[k] = (1/N) * sum_j accg[j]*W2[j][k] + b2[k] ----
__global__ __launch_bounds__(256) void k_gemv(const float* __restrict__ accg,
                                              const float* __restrict__ W2,
                                              const float* __restrict__ b2,
                                              float* __restrict__ out) {
    __shared__ float a[D], r2[D];
    int t = threadIdx.x, k = t & (D - 1), g = t >> 7;
    if (t < D) a[t] = accg[t];
    __syncthreads();
    float o = 0.f;
    int j0 = g * 64;
    #pragma unroll 16
    for (int j = j0; j < j0 + 64; ++j) o = fmaf(a[j], W2[j * D + k], o);
    if (g) r2[k] = o;
    __syncthreads();
    if (!g) out[k] = (o + r2[k]) * (1.0f / (float)NN) + b2[k];
}

extern "C" void kernel_launch(void* const* d_in, const int* in_sizes, int n_in,
                              void* d_out, int out_size, void* d_ws, size_t ws_size,
                              hipStream_t stream) {
    // inputs: 0=x (unused; ref overwrites with ones), 1=edge_index [2,E] int,
    //         2=edge_attr [E] f32, 3=W1, 4=b1, 5=W2, 6=b2 (all f32)
    const int* ei    = (const int*)d_in[1];
    const int4* row4 = (const int4*)ei;
    const int4* col4 = (const int4*)(ei + NE);
    const float4* w4 = (const float4*)d_in[2];
    const float* W1 = (const float*)d_in[3];
    const float* b1 = (const float*)d_in[4];
    const float* W2 = (const float*)d_in[5];
    const float* b2 = (const float*)d_in[6];
    float* out = (float*)d_out;

    float* ws   = (float*)d_ws;
    float* pA   = ws;                        // [P*NNP] deg partials, then S partials
    float* pB   = pA + (size_t)P * NNP;      // [P*NNP] U partials
    float* dinv = pB + (size_t)P * NNP;      // [NNP]
    float* s1   = dinv + NNP;                // [D]
    float* accg = s1 + D;                    // [D]
    float* valS = accg + D;                  // [NE]
    float* valU = valS + NE;                 // [NE]
    // total ~39 MB << ws_size

    k_scat1   <<<BINS * P, 1024, 0, stream>>>(col4, w4, pA);
    k_red1    <<<RB, 256, 0, stream>>>(pA, W1, dinv, s1, accg);
    k_val     <<<(NE4 + 255) / 256, 256, 0, stream>>>(row4, col4, w4, dinv,
                                                      (float4*)valS, (float4*)valU);
    k_scatSU  <<<2 * BINS * P, 1024, 0, stream>>>(col4, row4, (const float4*)valS,
                                                  (const float4*)valU, pA, pB);
    k_red2node<<<RB, 256, 0, stream>>>(pA, pB, dinv, s1, b1, accg);
    k_gemv    <<<1, 256, 0, stream>>>(accg, W2, b2, out);
}

// Round 9
// 161.548 us; speedup vs baseline: 1.0580x; 1.0580x over previous
//
#include <hip/hip_runtime.h>

#define NN    100000
#define NE    1600000
#define NE4   (NE / 4)
#define D     128
#define P     32                 // edge slices
#define BINS  8                  // node bins
#define BSZ   12512              // nodes per bin (50 KB LDS); BINS*BSZ = 100096 >= NN
#define NNP   (BINS * BSZ)       // padded node stride (100096 = 391*256)
#define NNP4  (NNP / 4)          // 25024 = 391*64
#define SL4   (NE4 / P)          // int4 edges per slice = 12500 (exact)
#define RB    391                // node-chunk blocks (391*64 float4 == NNP4 exactly)

// XCD swizzle: blocks scanning the same edge slice s land on one XCD (blk%8 == s%8),
// so each slice is HBM-fetched once and L2-served to the other 7 bin-blocks.
__device__ __forceinline__ void decode(int blk, int& b, int& s) {
    int x = blk & 7, y = blk >> 3;     // y in [0,32)
    s = (y & 3) * 8 + x;               // slice  [0,32)
    b = y >> 2;                        // bin    [0,8)
}

// ---- scatter 1: degree partials pA[s][v] = sum_{col=v, e in slice s} w[e] ----
__global__ __launch_bounds__(1024) void k_scat1(const int4* __restrict__ col4,
                                                const float4* __restrict__ w4,
                                                float* __restrict__ pA) {
    __shared__ float bin[BSZ];         // 50 KB -> 2 blocks/CU (32 waves)
    int b, s; decode(blockIdx.x, b, s);
    float4* bin4 = (float4*)bin;
    for (int i = threadIdx.x; i < BSZ / 4; i += 1024) bin4[i] = make_float4(0, 0, 0, 0);
    __syncthreads();
    const int lo = b * BSZ;
    const int e1 = (s + 1) * SL4;
    for (int e = s * SL4 + threadIdx.x; e < e1; e += 1024) {
        int4 k = col4[e];
        float4 v = w4[e];
        int r0 = k.x - lo, r1 = k.y - lo, r2 = k.z - lo, r3 = k.w - lo;
        if ((unsigned)r0 < (unsigned)BSZ) atomicAdd(&bin[r0], v.x);
        if ((unsigned)r1 < (unsigned)BSZ) atomicAdd(&bin[r1], v.y);
        if ((unsigned)r2 < (unsigned)BSZ) atomicAdd(&bin[r2], v.z);
        if ((unsigned)r3 < (unsigned)BSZ) atomicAdd(&bin[r3], v.w);
    }
    __syncthreads();
    float4* dst = (float4*)(pA + (size_t)s * NNP + lo);
    for (int i = threadIdx.x; i < BSZ / 4; i += 1024) dst[i] = bin4[i];
}

// ---- reduce 1: dinv = rsqrt(1 + deg); block 0: s1 = colsum(W1), accg = 0, ticket = 0 ----
__global__ __launch_bounds__(256) void k_red1(const float* __restrict__ pA,
                                              const float* __restrict__ W1,
                                              float* __restrict__ dinv,
                                              float* __restrict__ s1,
                                              float* __restrict__ accg,
                                              unsigned* __restrict__ ticket) {
    __shared__ float4 sS[256];
    __shared__ float red[256];
    const int t = threadIdx.x, q = t & 63, g = t >> 6;
    const int v4 = blockIdx.x * 64 + q;            // 391*64 == NNP4 exactly
    float4 a = make_float4(0.f, 0.f, 0.f, 0.f);
    #pragma unroll
    for (int k = 0; k < P / 4; ++k) {              // slice-split: group g sums 8 slices
        int ss = g * (P / 4) + k;
        float4 p = ((const float4*)(pA + (size_t)ss * NNP))[v4];
        a.x += p.x; a.y += p.y; a.z += p.z; a.w += p.w;
    }
    sS[t] = a;
    __syncthreads();
    if (t < 64) {
        float4 a0 = sS[t], a1 = sS[64 + t], a2 = sS[128 + t], a3 = sS[192 + t];
        float4 d;
        d.x = rsqrtf(1.f + a0.x + a1.x + a2.x + a3.x);   // +1 = self-loop weight
        d.y = rsqrtf(1.f + a0.y + a1.y + a2.y + a3.y);
        d.z = rsqrtf(1.f + a0.z + a1.z + a2.z + a3.z);
        d.w = rsqrtf(1.f + a0.w + a1.w + a2.w + a3.w);
        ((float4*)dinv)[v4] = d;
    }
    if (blockIdx.x == 0) {                         // s1[j] = sum_i W1[i][j]; zero accumulators
        int j = t & (D - 1), h = t >> 7;
        float p = 0.f;
        #pragma unroll 16
        for (int r = h * 64; r < h * 64 + 64; ++r) p += W1[r * D + j];
        red[t] = p;
        __syncthreads();
        if (t < D) {
            s1[t] = red[t] + red[t + D];
            accg[t] = 0.f;                         // ws re-poisoned each call
        }
        if (t == 0) *ticket = 0u;
    }
}

// ---- scatter 2 (fused, gated gathers): S[v]=sum_{col=v} w*dinv[row],
//      U[v]=sum_{row=v} w*dinv[col].  Exec-masked loads issue requests only for
//      active lanes -> total executed gathers = 2*NE (round-8 val-precompute was neutral-). 
__global__ __launch_bounds__(1024) void k_scat2(const int4* __restrict__ col4,
                                                const int4* __restrict__ row4,
                                                const float4* __restrict__ w4,
                                                const float* __restrict__ dinv,
                                                float* __restrict__ pS,
                                                float* __restrict__ pU) {
    __shared__ float binS[BSZ];
    __shared__ float binU[BSZ];        // 100 KB -> 1 block/CU (16 waves)
    int b, s; decode(blockIdx.x, b, s);
    float4* bS4 = (float4*)binS;
    float4* bU4 = (float4*)binU;
    for (int i = threadIdx.x; i < BSZ / 4; i += 1024) {
        bS4[i] = make_float4(0, 0, 0, 0);
        bU4[i] = make_float4(0, 0, 0, 0);
    }
    __syncthreads();
    const int lo = b * BSZ;
    const int e1 = (s + 1) * SL4;
    for (int e = s * SL4 + threadIdx.x; e < e1; e += 1024) {
        int4 kc = col4[e];
        int4 kr = row4[e];
        float4 w = w4[e];
        int c0 = kc.x - lo, c1 = kc.y - lo, c2 = kc.z - lo, c3 = kc.w - lo;
        int r0 = kr.x - lo, r1 = kr.y - lo, r2 = kr.z - lo, r3 = kr.w - lo;
        if ((unsigned)c0 < (unsigned)BSZ) atomicAdd(&binS[c0], w.x * dinv[kr.x]);
        if ((unsigned)c1 < (unsigned)BSZ) atomicAdd(&binS[c1], w.y * dinv[kr.y]);
        if ((unsigned)c2 < (unsigned)BSZ) atomicAdd(&binS[c2], w.z * dinv[kr.z]);
        if ((unsigned)c3 < (unsigned)BSZ) atomicAdd(&binS[c3], w.w * dinv[kr.w]);
        if ((unsigned)r0 < (unsigned)BSZ) atomicAdd(&binU[r0], w.x * dinv[kc.x]);
        if ((unsigned)r1 < (unsigned)BSZ) atomicAdd(&binU[r1], w.y * dinv[kc.y]);
        if ((unsigned)r2 < (unsigned)BSZ) atomicAdd(&binU[r2], w.z * dinv[kc.z]);
        if ((unsigned)r3 < (unsigned)BSZ) atomicAdd(&binU[r3], w.w * dinv[kc.w]);
    }
    __syncthreads();
    float4* dS = (float4*)(pS + (size_t)s * NNP + lo);
    float4* dU = (float4*)(pU + (size_t)s * NNP + lo);
    for (int i = threadIdx.x; i < BSZ / 4; i += 1024) { dS[i] = bS4[i]; dU[i] = bU4[i]; }
}

// ---- reduce 2 + node-dot + LAST-BLOCK gemv:
//  c = dinv*(S+dinv), wgt = dinv*(U+dinv);  accg[j] += sum_v wgt*relu(c*s1[j]+b1[j]);
//  last block: out[k] = (1/N)*sum_j accg[j]*W2[j][k] + b2[k]
__global__ __launch_bounds__(256) void k_red2node(const float* __restrict__ pS,
                                                  const float* __restrict__ pU,
                                                  const float* __restrict__ dinv,
                                                  const float* __restrict__ s1,
                                                  const float* __restrict__ b1,
                                                  const float* __restrict__ W2,
                                                  const float* __restrict__ b2,
                                                  float* __restrict__ accg,
                                                  unsigned* __restrict__ ticket,
                                                  float* __restrict__ out) {
    __shared__ float4 sS[256], sU[256];
    __shared__ float4 ldsC[64], ldsW[64];
    __shared__ float red[D], aG[D], r2[D];
    __shared__ unsigned stick;
    const int t = threadIdx.x;
    const int q = t & 63;
    const int grp = t >> 6;
    const int v4 = blockIdx.x * 64 + q;            // 391*64 == NNP4 exactly

    float4 S = make_float4(0, 0, 0, 0), U = make_float4(0, 0, 0, 0);
    #pragma unroll
    for (int k = 0; k < P / 4; ++k) {
        int ss = grp * (P / 4) + k;
        float4 a = ((const float4*)(pS + (size_t)ss * NNP))[v4];
        float4 u = ((const float4*)(pU + (size_t)ss * NNP))[v4];
        S.x += a.x; S.y += a.y; S.z += a.z; S.w += a.w;
        U.x += u.x; U.y += u.y; U.z += u.z; U.w += u.w;
    }
    sS[t] = S; sU[t] = U;
    __syncthreads();
    if (t < 64) {
        float4 S0 = sS[t], S1 = sS[64 + t], S2 = sS[128 + t], S3 = sS[192 + t];
        float4 U0 = sU[t], U1 = sU[64 + t], U2 = sU[128 + t], U3 = sU[192 + t];
        float4 Sa, Ua;
        Sa.x = S0.x + S1.x + S2.x + S3.x; Sa.y = S0.y + S1.y + S2.y + S3.y;
        Sa.z = S0.z + S1.z + S2.z + S3.z; Sa.w = S0.w + S1.w + S2.w + S3.w;
        Ua.x = U0.x + U1.x + U2.x + U3.x; Ua.y = U0.y + U1.y + U2.y + U3.y;
        Ua.z = U0.z + U1.z + U2.z + U3.z; Ua.w = U0.w + U1.w + U2.w + U3.w;
        float4 dv = ((const float4*)dinv)[v4];
        float4 cc, ww;
        cc.x = dv.x * (Sa.x + dv.x); cc.y = dv.y * (Sa.y + dv.y);
        cc.z = dv.z * (Sa.z + dv.z); cc.w = dv.w * (Sa.w + dv.w);
        ww.x = dv.x * (Ua.x + dv.x); ww.y = dv.y * (Ua.y + dv.y);
        ww.z = dv.z * (Ua.z + dv.z); ww.w = dv.w * (Ua.w + dv.w);
        int v0 = v4 * 4;                           // mask padded fake nodes
        if (v0 + 0 >= NN) ww.x = 0.f;
        if (v0 + 1 >= NN) ww.y = 0.f;
        if (v0 + 2 >= NN) ww.z = 0.f;
        if (v0 + 3 >= NN) ww.w = 0.f;
        ldsC[t] = cc; ldsW[t] = ww;
    }
    __syncthreads();

    const int j = t & (D - 1), g = t >> 7;
    const float sj = s1[j], bj = b1[j];
    float acc = 0.f;
    #pragma unroll
    for (int k = 0; k < 32; ++k) {
        float4 c4 = ldsC[g * 32 + k];              // wave-uniform LDS broadcast
        float4 w4 = ldsW[g * 32 + k];
        acc += w4.x * fmaxf(fmaf(c4.x, sj, bj), 0.f);
        acc += w4.y * fmaxf(fmaf(c4.y, sj, bj), 0.f);
        acc += w4.z * fmaxf(fmaf(c4.z, sj, bj), 0.f);
        acc += w4.w * fmaxf(fmaf(c4.w, sj, bj), 0.f);
    }
    if (g) red[j] = acc;
    __syncthreads();
    if (!g) atomicAdd(&accg[j], acc + red[j]);     // device-scope

    // ---- last-block epilogue (decoupled-lookback-style ticket) ----
    __syncthreads();                               // drains this block's atomics (vmcnt)
    if (t == 0) {
        __threadfence();                           // release accg adds
        stick = atomicAdd(ticket, 1u);
    }
    __syncthreads();
    if (stick == RB - 1) {                         // block-uniform condition
        __threadfence();                           // acquire other blocks' accg adds
        if (t < D)
            aG[t] = __hip_atomic_load(&accg[t], __ATOMIC_RELAXED, __HIP_MEMORY_SCOPE_AGENT);
        __syncthreads();
        float o = 0.f;
        #pragma unroll 16
        for (int k = 0; k < 64; ++k) {
            int jj = g * 64 + k;
            o = fmaf(aG[jj], W2[jj * D + j], o);
        }
        if (g) r2[j] = o;
        __syncthreads();
        if (!g) out[j] = (o + r2[j]) * (1.0f / (float)NN) + b2[j];
    }
}

extern "C" void kernel_launch(void* const* d_in, const int* in_sizes, int n_in,
                              void* d_out, int out_size, void* d_ws, size_t ws_size,
                              hipStream_t stream) {
    // inputs: 0=x (unused; ref overwrites with ones), 1=edge_index [2,E] int,
    //         2=edge_attr [E] f32, 3=W1, 4=b1, 5=W2, 6=b2 (all f32)
    const int* ei    = (const int*)d_in[1];
    const int4* row4 = (const int4*)ei;
    const int4* col4 = (const int4*)(ei + NE);
    const float4* w4 = (const float4*)d_in[2];
    const float* W1 = (const float*)d_in[3];
    const float* b1 = (const float*)d_in[4];
    const float* W2 = (const float*)d_in[5];
    const float* b2 = (const float*)d_in[6];
    float* out = (float*)d_out;

    float* ws   = (float*)d_ws;
    float* pA   = ws;                        // [P*NNP] deg partials, then S partials
    float* pB   = pA + (size_t)P * NNP;      // [P*NNP] U partials
    float* dinv = pB + (size_t)P * NNP;      // [NNP]
    float* s1   = dinv + NNP;                // [D]
    float* accg = s1 + D;                    // [D]
    unsigned* ticket = (unsigned*)(accg + D);
    // total ~26 MB << ws_size

    k_scat1   <<<BINS * P, 1024, 0, stream>>>(col4, w4, pA);
    k_red1    <<<RB, 256, 0, stream>>>(pA, W1, dinv, s1, accg, ticket);
    k_scat2   <<<BINS * P, 1024, 0, stream>>>(col4, row4, w4, dinv, pA, pB);
    k_red2node<<<RB, 256, 0, stream>>>(pA, pB, dinv, s1, b1, W2, b2, accg, ticket, out);
}